// Round 13
// baseline (174.233 us; speedup 1.0000x reference)
//
#include <hip/hip_runtime.h>
#include <stdint.h>

#define Bn 16
#define Sn 2048
#define Dn 128
#define QBLK 64
#define KVBLK 64
#define NTHR 256
#define NT (Sn / KVBLK)

typedef __attribute__((ext_vector_type(4))) float f32x4;
typedef __attribute__((ext_vector_type(16))) float f32x16;
typedef __attribute__((ext_vector_type(8))) short bf16x8;   // 8 bf16 = 4 VGPRs
typedef __attribute__((ext_vector_type(2))) unsigned int u32x2;

// LDS (main kernel):
//  K  : [64] rows stride 264 B, byte(k,d) = k*264 + 2d   (2-way banks, free) 16896 B
//  VT : [128] rows stride 136 B, byte(d,k) = d*136 + 2k  (2-way banks)       17408 B
//  xch: epilogue-only exchange overlays the two regions (qw*16896)
#define KSTRIDE 264
#define VTOFF 16896
#define VSTRIDE 136
#define SMEM_BYTES 34304

__device__ __forceinline__ uint32_t f2bf_u(float f) {   // fp32 -> bf16, round-nearest-away
  return (__float_as_uint(f) + 0x8000u) >> 16;
}
__device__ __forceinline__ uint32_t pk2(float a, float b) {
  return f2bf_u(a) | (f2bf_u(b) << 16);
}

// ---- prepass 1: K fp32 -> bf16 row-major (coalesced grid-stride) ----
__global__ __launch_bounds__(256) void cvt_k(const float* __restrict__ K,
                                             unsigned short* __restrict__ Kb) {
  const int n4 = Bn * Sn * Dn / 4;
  for (int i = blockIdx.x * 256 + threadIdx.x; i < n4; i += gridDim.x * 256) {
    const float4 v = ((const float4*)K)[i];
    u32x2 o;
    o.x = pk2(v.x, v.y);
    o.y = pk2(v.z, v.w);
    ((u32x2*)Kb)[i] = o;
  }
}

// ---- prepass 2: V fp32 -> bf16 transposed, tile-blocked [b][kt][d][64k] ----
__global__ __launch_bounds__(256) void tr_v(const float* __restrict__ V,
                                            unsigned short* __restrict__ Vt) {
  __shared__ unsigned short lds[64 * 130];   // [k][d], stride 130 elems
  const int tid = threadIdx.x;
  const int b = blockIdx.x >> 5;
  const int kt = blockIdx.x & 31;
  const float* src = V + ((size_t)b * Sn + kt * 64) * Dn;
  // phase 1: read rows coalesced, cvt, store to LDS
#pragma unroll
  for (int it = 0; it < 8; ++it) {
    const int gr = it * 256 + tid;           // float4 granule: 64k x 32
    const int k = gr >> 5, g4 = gr & 31;
    const float4 v = ((const float4*)src)[gr];
    unsigned short* p = &lds[k * 130 + g4 * 4];
    p[0] = (unsigned short)f2bf_u(v.x);
    p[1] = (unsigned short)f2bf_u(v.y);
    p[2] = (unsigned short)f2bf_u(v.z);
    p[3] = (unsigned short)f2bf_u(v.w);
  }
  __syncthreads();
  // phase 2: write columns coalesced: out[d][64k], 16B granule = 8 k
  unsigned short* dst = Vt + (size_t)(b * 32 + kt) * (Dn * 64);
#pragma unroll
  for (int it = 0; it < 4; ++it) {
    const int gr = it * 256 + tid;           // 128 d x 8 granules
    const int d = gr >> 3, c = gr & 7;
    ushort4 a, bb;
    a.x = lds[(c * 8 + 0) * 130 + d]; a.y = lds[(c * 8 + 1) * 130 + d];
    a.z = lds[(c * 8 + 2) * 130 + d]; a.w = lds[(c * 8 + 3) * 130 + d];
    bb.x = lds[(c * 8 + 4) * 130 + d]; bb.y = lds[(c * 8 + 5) * 130 + d];
    bb.z = lds[(c * 8 + 6) * 130 + d]; bb.w = lds[(c * 8 + 7) * 130 + d];
    uint4 o;
    o.x = a.x | ((uint32_t)a.y << 16);  o.y = a.z | ((uint32_t)a.w << 16);
    o.z = bb.x | ((uint32_t)bb.y << 16); o.w = bb.z | ((uint32_t)bb.w << 16);
    *(uint4*)(dst + d * 64 + c * 8) = o;
  }
}

// ---- main kernel: bf16 K/VT sources, pure-copy staging ----
__global__ __launch_bounds__(NTHR, 2) void attn_fwd(
    const float* __restrict__ Q, const unsigned short* __restrict__ Kb,
    const unsigned short* __restrict__ Vt, float* __restrict__ O) {
  __shared__ uint4 smem_[SMEM_BYTES / 16];
  char* smem = (char*)smem_;

  const int tid = threadIdx.x;
  const int lane = tid & 63;
  const int w = tid >> 6;        // wave 0..3
  const int qw = w & 1;          // q sub-tile (32 rows)
  const int h = w >> 1;          // k sub-range of tile (32 rows)
  const int hi = lane >> 5;      // half-wave 0/1
  const int ql = lane & 31;      // q / k-row / d-row selector

  // XCD-aware swizzle: i&7 -> XCD; each XCD's L2 holds ~2 batches' K/V.
  const int i = blockIdx.x;
  const int j = i >> 3;
  const int b = (i & 7) + 8 * (j & 1);
  const int q0 = (j >> 1) * QBLK;
  const int qg = q0 + qw * 32 + ql;

  // ---- Q in registers: B-operand of swapped QK^T. col=q=lane&31, kd=8*hi+jj ----
  const float qscale = 0.08838834764831845f * 1.44269504088896340736f; // 1/sqrt(128)*log2e
  bf16x8 qf[8];
  {
    const float* qrow = Q + (size_t)(b * Sn + qg) * Dn;
#pragma unroll
    for (int dk = 0; dk < 8; ++dk) {
      const int d0 = dk * 16 + hi * 8;
      const float4 a = *(const float4*)(qrow + d0);
      const float4 d = *(const float4*)(qrow + d0 + 4);
      bf16x8 q8;
      q8[0] = (short)f2bf_u(a.x * qscale); q8[1] = (short)f2bf_u(a.y * qscale);
      q8[2] = (short)f2bf_u(a.z * qscale); q8[3] = (short)f2bf_u(a.w * qscale);
      q8[4] = (short)f2bf_u(d.x * qscale); q8[5] = (short)f2bf_u(d.y * qscale);
      q8[6] = (short)f2bf_u(d.z * qscale); q8[7] = (short)f2bf_u(d.w * qscale);
      qf[dk] = q8;
    }
  }

  f32x16 o[4];
#pragma unroll
  for (int dt = 0; dt < 4; ++dt) {
#pragma unroll
    for (int jj = 0; jj < 16; ++jj) o[dt][jj] = 0.f;
  }
  float m_r = -1.0e30f, l_r = 0.f;

  const char* Kg = (const char*)(Kb + (size_t)b * Sn * Dn);       // bf16 rows, 256 B
  const char* Vg = (const char*)(Vt + (size_t)b * 32 * (Dn * 64));// 16 KB tiles

  for (int t = 0; t < NT; ++t) {
    __syncthreads();   // prev tile's LDS reads done; regions free for staging

    // ---- stage K tile: pure bf16 copy, 4x dwordx4 each ----
    {
      const char* src = Kg + (size_t)t * (KVBLK * 256);
#pragma unroll
      for (int it = 0; it < 4; ++it) {
        const int gr = it * NTHR + tid;      // 16B granule: 64 rows x 16
        const int k = gr >> 4, c = gr & 15;
        *(uint4*)(smem + k * KSTRIDE + c * 16) =
            *(const uint4*)(src + k * 256 + c * 16);
      }
    }
    // ---- stage VT tile: pure bf16 copy, 4x dwordx4 each ----
    {
      const char* src = Vg + (size_t)t * 16384;
#pragma unroll
      for (int it = 0; it < 4; ++it) {
        const int gr = it * NTHR + tid;      // 16B granule: 128 rows x 8
        const int d = gr >> 3, c = gr & 7;
        *(uint4*)(smem + VTOFF + d * VSTRIDE + c * 16) =
            *(const uint4*)(src + d * 128 + c * 16);
      }
    }
    __syncthreads();

    // ---- swapped QK^T: S^T[k'][q] over this wave's 32-row k-subset ----
    f32x16 s;
#pragma unroll
    for (int jj = 0; jj < 16; ++jj) s[jj] = 0.f;
    __builtin_amdgcn_s_setprio(1);
#pragma unroll
    for (int dk = 0; dk < 8; ++dk) {
      bf16x8 a = *(const bf16x8*)(smem + (32 * h + ql) * KSTRIDE +
                                  dk * 32 + hi * 16);
      s = __builtin_amdgcn_mfma_f32_32x32x16_bf16(a, qf[dk], s, 0, 0, 0);
    }
    __builtin_amdgcn_s_setprio(0);
    // lane holds, for q=ql: k' = 32h + (r&3) + 8*(r>>2) + 4*hi, r=0..15

    // ---- in-register online softmax (per-wave m,l over its k') ----
    float x0 = fmaxf(fmaxf(s[0], s[1]), fmaxf(s[2], s[3]));
    float x1 = fmaxf(fmaxf(s[4], s[5]), fmaxf(s[6], s[7]));
    float x2 = fmaxf(fmaxf(s[8], s[9]), fmaxf(s[10], s[11]));
    float x3 = fmaxf(fmaxf(s[12], s[13]), fmaxf(s[14], s[15]));
    float pm = fmaxf(fmaxf(x0, x1), fmaxf(x2, x3));
    pm = fmaxf(pm, __shfl_xor(pm, 32, 64));

    if (!__all(pm <= m_r + 8.0f)) {   // defer-max (T13)
      const float mnew = fmaxf(m_r, pm);
      const float alpha = __builtin_amdgcn_exp2f(m_r - mnew);
      l_r *= alpha;
#pragma unroll
      for (int dt = 0; dt < 4; ++dt) o[dt] *= alpha;
      m_r = mnew;
    }

#pragma unroll
    for (int jj = 0; jj < 16; ++jj) s[jj] = __builtin_amdgcn_exp2f(s[jj] - m_r);
    {
      float r0 = 0.f, r1 = 0.f, r2 = 0.f, r3 = 0.f;
#pragma unroll
      for (int jj = 0; jj < 4; ++jj) {
        r0 += s[jj]; r1 += s[4 + jj]; r2 += s[8 + jj]; r3 += s[12 + jj];
      }
      float rsum = (r0 + r1) + (r2 + r3);
      l_r += rsum + __shfl_xor(rsum, 32, 64);
    }

    // ---- pack P to bf16 + half-exchange with lane^32 -> PV B-fragments ----
    uint32_t own[4][2];
#pragma unroll
    for (int mm = 0; mm < 4; ++mm) {
      own[mm][0] = pk2(s[4 * mm + 0], s[4 * mm + 1]);
      own[mm][1] = pk2(s[4 * mm + 2], s[4 * mm + 3]);
    }
    uint32_t rcv[2][2];
#pragma unroll
    for (int jj = 0; jj < 2; ++jj)
#pragma unroll
      for (int e = 0; e < 2; ++e) {
        uint32_t sel = hi ? own[2 * jj][e] : own[2 * jj + 1][e];
        rcv[jj][e] = (uint32_t)__shfl_xor((int)sel, 32, 64);
      }
    bf16x8 pb[2];
#pragma unroll
    for (int ks = 0; ks < 2; ++ks) {
      union { uint32_t u[4]; bf16x8 v; } tt;
      tt.u[0] = hi ? rcv[ks][0] : own[2 * ks][0];
      tt.u[1] = hi ? rcv[ks][1] : own[2 * ks][1];
      tt.u[2] = hi ? own[2 * ks + 1][0] : rcv[ks][0];
      tt.u[3] = hi ? own[2 * ks + 1][1] : rcv[ks][1];
      pb[ks] = tt.v;
    }

    // ---- PV as O^T = V^T·P^T: A-frags from LDS VT (k' = 32h + ks*16 + 8hi + jj) ----
    __builtin_amdgcn_s_setprio(1);
#pragma unroll
    for (int dt = 0; dt < 4; ++dt) {
      const uint32_t vbase =
          (uint32_t)(VTOFF + (dt * 32 + ql) * VSTRIDE + 64 * h + 16 * hi);
#pragma unroll
      for (int ks = 0; ks < 2; ++ks) {
        bf16x8 a = *(const bf16x8*)(smem + vbase + ks * 32);
        o[dt] = __builtin_amdgcn_mfma_f32_32x32x16_bf16(a, pb[ks], o[dt], 0, 0, 0);
      }
    }
    __builtin_amdgcn_s_setprio(0);
  }

  // ---- merge the two k-subset partials (w <-> w^2) in LDS, then store ----
  __syncthreads();
  char* xch = smem + qw * 16896;
  if (h) {                       // k-half 1: writer
#pragma unroll
    for (int dt = 0; dt < 4; ++dt) {
#pragma unroll
      for (int q2 = 0; q2 < 4; ++q2) {
        float4 v;
        v.x = o[dt][4 * q2 + 0]; v.y = o[dt][4 * q2 + 1];
        v.z = o[dt][4 * q2 + 2]; v.w = o[dt][4 * q2 + 3];
        *(float4*)(xch + (dt * 4 + q2) * 1024 + lane * 16) = v;
      }
    }
    *(float2*)(xch + 16384 + lane * 8) = make_float2(m_r, l_r);
  }
  __syncthreads();
  if (!h) {                      // k-half 0: merger + storer
    const float2 ml1v = *(const float2*)(xch + 16384 + lane * 8);
    const float M = fmaxf(m_r, ml1v.x);
    const float w0 = __builtin_amdgcn_exp2f(m_r - M);
    const float w1 = __builtin_amdgcn_exp2f(ml1v.x - M);
    const float inv = 1.0f / (l_r * w0 + ml1v.y * w1);
    const float s0 = w0 * inv, s1 = w1 * inv;
    float* orow = O + (size_t)(b * Sn + qg) * Dn;
#pragma unroll
    for (int dt = 0; dt < 4; ++dt) {
#pragma unroll
      for (int q2 = 0; q2 < 4; ++q2) {
        const float4 o1v =
            *(const float4*)(xch + (dt * 4 + q2) * 1024 + lane * 16);
        float4 v;
        v.x = o[dt][4 * q2 + 0] * s0 + o1v.x * s1;
        v.y = o[dt][4 * q2 + 1] * s0 + o1v.y * s1;
        v.z = o[dt][4 * q2 + 2] * s0 + o1v.z * s1;
        v.w = o[dt][4 * q2 + 3] * s0 + o1v.w * s1;
        *(float4*)(orow + dt * 32 + q2 * 8 + hi * 4) = v;
      }
    }
  }
}

extern "C" void kernel_launch(void* const* d_in, const int* in_sizes, int n_in,
                              void* d_out, int out_size, void* d_ws, size_t ws_size,
                              hipStream_t stream) {
  (void)in_sizes; (void)n_in; (void)out_size; (void)ws_size;
  const float* Q = (const float*)d_in[0];
  const float* K = (const float*)d_in[1];
  const float* V = (const float*)d_in[2];
  float* O = (float*)d_out;

  // ws layout: Kb (8.39 MB bf16) | Vt (8.39 MB bf16). ws_size >= 17.3 MB
  // verified empirically in round 12 (split path ran with that need).
  unsigned short* Kb = (unsigned short*)d_ws;
  unsigned short* Vt = Kb + (size_t)Bn * Sn * Dn;

  cvt_k<<<dim3(2048, 1, 1), dim3(256, 1, 1), 0, stream>>>(K, Kb);
  tr_v<<<dim3(Bn * 32, 1, 1), dim3(256, 1, 1), 0, stream>>>(V, Vt);
  attn_fwd<<<dim3((Sn / QBLK) * Bn, 1, 1), dim3(NTHR, 1, 1), 0, stream>>>(
      Q, Kb, Vt, O);
}

// Round 14
// 81.562 us; speedup vs baseline: 2.1362x; 2.1362x over previous
//
#include <hip/hip_runtime.h>
#include <stdint.h>

#define Bn 16
#define Sn 2048
#define Dn 128
#define QBLK 64
#define KVBLK 64
#define NTHR 256
#define NT (Sn / KVBLK)

typedef __attribute__((ext_vector_type(4))) float f32x4;
typedef __attribute__((ext_vector_type(16))) float f32x16;
typedef __attribute__((ext_vector_type(8))) short bf16x8;   // 8 bf16 = 4 VGPRs
typedef __attribute__((ext_vector_type(2))) unsigned int u32x2;

// LDS:
//  K double-buffer: 2 x 16384 B, LINEAR tiles holding PRE-SWIZZLED content:
//    byte(k,d-granule c) = (k*256 + c*16) ^ ((k&7)<<4)   [baked in by cvt_k]
//    b128 read at row r, ofs dk*32+hi*16, XOR (r&7)<<4 -> 2-way banks (free)
//  xch: epilogue-only exchange overlays both buffers (qw*16896, 16896 B each)
#define SMEM_BYTES 33792

__device__ __forceinline__ uint32_t f2bf_u(float f) {   // fp32 -> bf16, round-nearest-away
  return (__float_as_uint(f) + 0x8000u) >> 16;
}
__device__ __forceinline__ uint32_t pk2(float a, float b) {
  return f2bf_u(a) | (f2bf_u(b) << 16);
}

// ---- prepass: K fp32 -> bf16, tiled [b][t][16KB], XOR-swizzle baked in ----
__global__ __launch_bounds__(256) void cvt_k(const float* __restrict__ K,
                                             unsigned short* __restrict__ Kb) {
  const int g = blockIdx.x * 256 + threadIdx.x;   // [b<16][t<32][k<64][c<16]
  const int c = g & 15, k = (g >> 4) & 63;
  const int t = (g >> 10) & 31, b = g >> 15;
  const float* src = K + ((size_t)b * Sn + t * 64 + k) * Dn + c * 8;
  const float4 a = *(const float4*)src;
  const float4 d = *(const float4*)(src + 4);
  uint4 o;
  o.x = pk2(a.x, a.y); o.y = pk2(a.z, a.w);
  o.z = pk2(d.x, d.y); o.w = pk2(d.z, d.w);
  const uint32_t off = (uint32_t)(k * 256 + c * 16) ^ ((uint32_t)(k & 7) << 4);
  *(uint4*)((char*)Kb + ((size_t)b * 32 + t) * 16384 + off) = o;
}

__global__ __launch_bounds__(NTHR, 2) void attn_fwd(
    const float* __restrict__ Q, const unsigned short* __restrict__ Kb,
    const float* __restrict__ V, float* __restrict__ O) {
  __shared__ uint4 smem_[SMEM_BYTES / 16];
  char* smem = (char*)smem_;

  const int tid = threadIdx.x;
  const int lane = tid & 63;
  const int w = tid >> 6;        // wave 0..3
  const int qw = w & 1;          // q sub-tile (32 rows)
  const int h = w >> 1;          // k sub-range of tile (32 rows)
  const int hi = lane >> 5;      // half-wave 0/1
  const int ql = lane & 31;      // q / k-row / d-row selector

  // XCD-aware swizzle: i&7 -> XCD; each XCD's L2 holds ~2 batches' K/V.
  const int i = blockIdx.x;
  const int j = i >> 3;
  const int b = (i & 7) + 8 * (j & 1);
  const int q0 = (j >> 1) * QBLK;
  const int qg = q0 + qw * 32 + ql;

  // ---- Q in registers: B-operand of swapped QK^T. col=q=lane&31, kd=8*hi+jj ----
  const float qscale = 0.08838834764831845f * 1.44269504088896340736f; // 1/sqrt(128)*log2e
  bf16x8 qf[8];
  {
    const float* qrow = Q + (size_t)(b * Sn + qg) * Dn;
#pragma unroll
    for (int dk = 0; dk < 8; ++dk) {
      const int d0 = dk * 16 + hi * 8;
      const float4 a = *(const float4*)(qrow + d0);
      const float4 d = *(const float4*)(qrow + d0 + 4);
      bf16x8 q8;
      q8[0] = (short)f2bf_u(a.x * qscale); q8[1] = (short)f2bf_u(a.y * qscale);
      q8[2] = (short)f2bf_u(a.z * qscale); q8[3] = (short)f2bf_u(a.w * qscale);
      q8[4] = (short)f2bf_u(d.x * qscale); q8[5] = (short)f2bf_u(d.y * qscale);
      q8[6] = (short)f2bf_u(d.z * qscale); q8[7] = (short)f2bf_u(d.w * qscale);
      qf[dk] = q8;
    }
  }

  f32x16 o[4];
#pragma unroll
  for (int dt = 0; dt < 4; ++dt) {
#pragma unroll
    for (int jj = 0; jj < 16; ++jj) o[dt][jj] = 0.f;
  }
  float m_r = -1.0e30f, l_r = 0.f;

  const char* Kg = (const char*)(Kb + (size_t)b * Sn * Dn);   // 32 x 16KB tiles
  const float* Vg_base = V + (size_t)b * Sn * Dn;

  // async K staging: wave w copies rows [16w,16w+16) = 4KB, 4 x 16B per lane.
  // LDS dest is wave-uniform base + lane*16 (HW); source is per-lane.
#define STAGE_K(t_, dstoff_)                                                   \
  {                                                                            \
    const char* gsrc = Kg + (size_t)(t_)*16384 + w * 4096 + lane * 16;         \
    char* ldst = smem + (dstoff_) + w * 4096;                                  \
    _Pragma("unroll") for (int it = 0; it < 4; ++it) {                         \
      __builtin_amdgcn_global_load_lds(                                        \
          (const __attribute__((address_space(1))) uint32_t*)(gsrc + it * 1024),\
          (__attribute__((address_space(3))) uint32_t*)(ldst + it * 1024),     \
          16, 0, 0);                                                           \
    }                                                                          \
  }

  STAGE_K(0, 0)
  __syncthreads();   // drains vmcnt(0): tile 0 resident

  for (int t = 0; t < NT; ++t) {
    const uint32_t cb = (uint32_t)(t & 1) * 16384;
    if (t < NT - 1) STAGE_K(t + 1, 16384 - cb)   // async; drains at loop barrier

    const int kvk = t * KVBLK + 32 * h;          // this wave's 32-row k slice

    // ---- issue ALL V fragment loads (direct global, coalesced 2x128B/instr);
    //      latency hides under QK^T + softmax ----
    float vf[8][8];
    {
      const float* vb = Vg_base + (size_t)kvk * Dn + 8 * hi * Dn + ql;
#pragma unroll
      for (int dt = 0; dt < 4; ++dt)
#pragma unroll
        for (int ks = 0; ks < 2; ++ks)
#pragma unroll
          for (int jj = 0; jj < 8; ++jj)
            vf[dt * 2 + ks][jj] = vb[(ks * 16 + jj) * Dn + dt * 32];
    }

    // ---- swapped QK^T: S^T[k'][q] over this wave's 32-row k-subset ----
    f32x16 s;
#pragma unroll
    for (int jj = 0; jj < 16; ++jj) s[jj] = 0.f;
    __builtin_amdgcn_s_setprio(1);
#pragma unroll
    for (int dk = 0; dk < 8; ++dk) {
      const uint32_t koff =
          (uint32_t)((32 * h + ql) * 256 + dk * 32 + hi * 16) ^
          ((uint32_t)(ql & 7) << 4);
      bf16x8 a = *(const bf16x8*)(smem + cb + koff);
      s = __builtin_amdgcn_mfma_f32_32x32x16_bf16(a, qf[dk], s, 0, 0, 0);
    }
    __builtin_amdgcn_s_setprio(0);
    // lane holds, for q=ql: k' = 32h + (r&3) + 8*(r>>2) + 4*hi, r=0..15

    // ---- in-register online softmax (per-wave m,l over its k') ----
    float x0 = fmaxf(fmaxf(s[0], s[1]), fmaxf(s[2], s[3]));
    float x1 = fmaxf(fmaxf(s[4], s[5]), fmaxf(s[6], s[7]));
    float x2 = fmaxf(fmaxf(s[8], s[9]), fmaxf(s[10], s[11]));
    float x3 = fmaxf(fmaxf(s[12], s[13]), fmaxf(s[14], s[15]));
    float pm = fmaxf(fmaxf(x0, x1), fmaxf(x2, x3));
    pm = fmaxf(pm, __shfl_xor(pm, 32, 64));

    if (!__all(pm <= m_r + 8.0f)) {   // defer-max (T13)
      const float mnew = fmaxf(m_r, pm);
      const float alpha = __builtin_amdgcn_exp2f(m_r - mnew);
      l_r *= alpha;
#pragma unroll
      for (int dt = 0; dt < 4; ++dt) o[dt] *= alpha;
      m_r = mnew;
    }

#pragma unroll
    for (int jj = 0; jj < 16; ++jj) s[jj] = __builtin_amdgcn_exp2f(s[jj] - m_r);
    {
      float r0 = 0.f, r1 = 0.f, r2 = 0.f, r3 = 0.f;
#pragma unroll
      for (int jj = 0; jj < 4; ++jj) {
        r0 += s[jj]; r1 += s[4 + jj]; r2 += s[8 + jj]; r3 += s[12 + jj];
      }
      float rsum = (r0 + r1) + (r2 + r3);
      l_r += rsum + __shfl_xor(rsum, 32, 64);
    }

    // ---- pack P to bf16 + half-exchange with lane^32 -> PV B-fragments ----
    uint32_t own[4][2];
#pragma unroll
    for (int mm = 0; mm < 4; ++mm) {
      own[mm][0] = pk2(s[4 * mm + 0], s[4 * mm + 1]);
      own[mm][1] = pk2(s[4 * mm + 2], s[4 * mm + 3]);
    }
    uint32_t rcv[2][2];
#pragma unroll
    for (int jj = 0; jj < 2; ++jj)
#pragma unroll
      for (int e = 0; e < 2; ++e) {
        uint32_t sel = hi ? own[2 * jj][e] : own[2 * jj + 1][e];
        rcv[jj][e] = (uint32_t)__shfl_xor((int)sel, 32, 64);
      }
    bf16x8 pb[2];
#pragma unroll
    for (int ks = 0; ks < 2; ++ks) {
      union { uint32_t u[4]; bf16x8 v; } tt;
      tt.u[0] = hi ? rcv[ks][0] : own[2 * ks][0];
      tt.u[1] = hi ? rcv[ks][1] : own[2 * ks][1];
      tt.u[2] = hi ? own[2 * ks + 1][0] : rcv[ks][0];
      tt.u[3] = hi ? own[2 * ks + 1][1] : rcv[ks][1];
      pb[ks] = tt.v;
    }

    // ---- PV as O^T = V^T·P^T: A-frags converted from the hoisted V loads ----
    __builtin_amdgcn_s_setprio(1);
#pragma unroll
    for (int dt = 0; dt < 4; ++dt) {
#pragma unroll
      for (int ks = 0; ks < 2; ++ks) {
        const int f = dt * 2 + ks;
        union { uint32_t u[4]; bf16x8 v; } tv;
        tv.u[0] = pk2(vf[f][0], vf[f][1]);
        tv.u[1] = pk2(vf[f][2], vf[f][3]);
        tv.u[2] = pk2(vf[f][4], vf[f][5]);
        tv.u[3] = pk2(vf[f][6], vf[f][7]);
        o[dt] = __builtin_amdgcn_mfma_f32_32x32x16_bf16(tv.v, pb[ks], o[dt], 0, 0, 0);
      }
    }
    __builtin_amdgcn_s_setprio(0);

    __syncthreads();   // drains vmcnt(0): staged tile t+1 resident; readers done
  }

  // ---- merge the two k-subset partials (w <-> w^2) in LDS, then store ----
  char* xch = smem + qw * 16896;
  if (h) {                       // k-half 1: writer
#pragma unroll
    for (int dt = 0; dt < 4; ++dt) {
#pragma unroll
      for (int q2 = 0; q2 < 4; ++q2) {
        float4 v;
        v.x = o[dt][4 * q2 + 0]; v.y = o[dt][4 * q2 + 1];
        v.z = o[dt][4 * q2 + 2]; v.w = o[dt][4 * q2 + 3];
        *(float4*)(xch + (dt * 4 + q2) * 1024 + lane * 16) = v;
      }
    }
    *(float2*)(xch + 16384 + lane * 8) = make_float2(m_r, l_r);
  }
  __syncthreads();
  if (!h) {                      // k-half 0: merger + storer
    const float2 ml1v = *(const float2*)(xch + 16384 + lane * 8);
    const float M = fmaxf(m_r, ml1v.x);
    const float w0 = __builtin_amdgcn_exp2f(m_r - M);
    const float w1 = __builtin_amdgcn_exp2f(ml1v.x - M);
    const float inv = 1.0f / (l_r * w0 + ml1v.y * w1);
    const float s0 = w0 * inv, s1 = w1 * inv;
    float* orow = O + (size_t)(b * Sn + qg) * Dn;
#pragma unroll
    for (int dt = 0; dt < 4; ++dt) {
#pragma unroll
      for (int q2 = 0; q2 < 4; ++q2) {
        const float4 o1v =
            *(const float4*)(xch + (dt * 4 + q2) * 1024 + lane * 16);
        float4 v;
        v.x = o[dt][4 * q2 + 0] * s0 + o1v.x * s1;
        v.y = o[dt][4 * q2 + 1] * s0 + o1v.y * s1;
        v.z = o[dt][4 * q2 + 2] * s0 + o1v.z * s1;
        v.w = o[dt][4 * q2 + 3] * s0 + o1v.w * s1;
        *(float4*)(orow + dt * 32 + q2 * 8 + hi * 4) = v;
      }
    }
  }
}

extern "C" void kernel_launch(void* const* d_in, const int* in_sizes, int n_in,
                              void* d_out, int out_size, void* d_ws, size_t ws_size,
                              hipStream_t stream) {
  (void)in_sizes; (void)n_in; (void)out_size; (void)ws_size;
  const float* Q = (const float*)d_in[0];
  const float* K = (const float*)d_in[1];
  const float* V = (const float*)d_in[2];
  float* O = (float*)d_out;

  // ws: Kb = 16 batches x 32 tiles x 16 KB (8.39 MB) of pre-swizzled bf16 K.
  unsigned short* Kb = (unsigned short*)d_ws;

  cvt_k<<<dim3(2048, 1, 1), dim3(256, 1, 1), 0, stream>>>(K, Kb);
  attn_fwd<<<dim3((Sn / QBLK) * Bn, 1, 1), dim3(NTHR, 1, 1), 0, stream>>>(
      Q, Kb, V, O);
}

// Round 15
// 69.033 us; speedup vs baseline: 2.5239x; 1.1815x over previous
//
#include <hip/hip_runtime.h>
#include <stdint.h>

#define Bn 16
#define Sn 2048
#define Dn 128
#define QBLK 64
#define KVBLK 64
#define NTHR 256
#define NT (Sn / KVBLK)

typedef __attribute__((ext_vector_type(4))) float f32x4;
typedef __attribute__((ext_vector_type(16))) float f32x16;
typedef __attribute__((ext_vector_type(8))) short bf16x8;   // 8 bf16 = 4 VGPRs
typedef __attribute__((ext_vector_type(2))) unsigned int u32x2;

// LDS:
//  K double-buffer: 2 x 16384 B, LINEAR tiles holding PRE-SWIZZLED content:
//    byte(k,c) = (k*256 + c*16) ^ ((k&7)<<4)   [baked in by cvt_k]
//  xch: epilogue-only exchange overlays both buffers (qw*16896)
#define SMEM_BYTES 33792

__device__ __forceinline__ uint32_t f2bf_u(float f) {   // fp32 -> bf16, round-nearest-away
  return (__float_as_uint(f) + 0x8000u) >> 16;
}
__device__ __forceinline__ uint32_t pk2(float a, float b) {
  return f2bf_u(a) | (f2bf_u(b) << 16);
}

// ---- prepass 1: K fp32 -> bf16, tiled [b][t][16KB], XOR-swizzle baked in ----
__global__ __launch_bounds__(256) void cvt_k(const float* __restrict__ K,
                                             unsigned short* __restrict__ Kb) {
  const int g = blockIdx.x * 256 + threadIdx.x;   // [b<16][t<32][k<64][c<16]
  const int c = g & 15, k = (g >> 4) & 63;
  const int t = (g >> 10) & 31, b = g >> 15;
  const float* src = K + ((size_t)b * Sn + t * 64 + k) * Dn + c * 8;
  const float4 a = *(const float4*)src;
  const float4 d = *(const float4*)(src + 4);
  uint4 o;
  o.x = pk2(a.x, a.y); o.y = pk2(a.z, a.w);
  o.z = pk2(d.x, d.y); o.w = pk2(d.z, d.w);
  const uint32_t off = (uint32_t)(k * 256 + c * 16) ^ ((uint32_t)(k & 7) << 4);
  *(uint4*)((char*)Kb + ((size_t)b * 32 + t) * 16384 + off) = o;
}

// ---- prepass 2: V fp32 -> bf16 PV-fragment layout ----
// Vf[b][t][h<2][f3<8][lane<64][8 bf16], granule(h,f3,lane) holds
// V[t*64 + 32h + (f3&1)*16 + 8*(lane>>5) + j][(f3>>1)*32 + (lane&31)], j=0..7
__global__ __launch_bounds__(256) void tr_v(const float* __restrict__ V,
                                            unsigned short* __restrict__ Vf) {
  __shared__ unsigned short lds[64 * 130];   // [k][d], stride 130 elems
  const int tid = threadIdx.x;
  const int b = blockIdx.x >> 5;
  const int t = blockIdx.x & 31;
  const float* src = V + ((size_t)b * Sn + t * 64) * Dn;
  // phase 1: read rows coalesced, cvt, store to LDS
#pragma unroll
  for (int it = 0; it < 8; ++it) {
    const int gr = it * 256 + tid;           // float4 granule: 64k x 32
    const int k = gr >> 5, g4 = gr & 31;
    const float4 v = ((const float4*)src)[gr];
    unsigned short* p = &lds[k * 130 + g4 * 4];
    p[0] = (unsigned short)f2bf_u(v.x);
    p[1] = (unsigned short)f2bf_u(v.y);
    p[2] = (unsigned short)f2bf_u(v.z);
    p[3] = (unsigned short)f2bf_u(v.w);
  }
  __syncthreads();
  // phase 2: write fragment granules (16B each), coalesced
  char* dst = (char*)Vf + (size_t)blockIdx.x * 16384;
#pragma unroll
  for (int it = 0; it < 4; ++it) {
    const int g = it * 256 + tid;            // granule id 0..1023
    const int lane = g & 63, f3 = (g >> 6) & 7, h = g >> 9;
    const int d = (f3 >> 1) * 32 + (lane & 31);
    const int k0 = 32 * h + (f3 & 1) * 16 + 8 * (lane >> 5);
    uint4 o;
    o.x = (uint32_t)lds[(k0 + 0) * 130 + d] | ((uint32_t)lds[(k0 + 1) * 130 + d] << 16);
    o.y = (uint32_t)lds[(k0 + 2) * 130 + d] | ((uint32_t)lds[(k0 + 3) * 130 + d] << 16);
    o.z = (uint32_t)lds[(k0 + 4) * 130 + d] | ((uint32_t)lds[(k0 + 5) * 130 + d] << 16);
    o.w = (uint32_t)lds[(k0 + 6) * 130 + d] | ((uint32_t)lds[(k0 + 7) * 130 + d] << 16);
    *(uint4*)(dst + g * 16) = o;
  }
}

__global__ __launch_bounds__(NTHR, 2) void attn_fwd(
    const float* __restrict__ Q, const unsigned short* __restrict__ Kb,
    const unsigned short* __restrict__ Vf, float* __restrict__ O) {
  __shared__ uint4 smem_[SMEM_BYTES / 16];
  char* smem = (char*)smem_;

  const int tid = threadIdx.x;
  const int lane = tid & 63;
  const int w = tid >> 6;        // wave 0..3
  const int qw = w & 1;          // q sub-tile (32 rows)
  const int h = w >> 1;          // k sub-range of tile (32 rows)
  const int hi = lane >> 5;      // half-wave 0/1
  const int ql = lane & 31;      // q / k-row / d-row selector

  // XCD-aware swizzle: i&7 -> XCD; each XCD's L2 holds ~2 batches' K/V.
  const int i = blockIdx.x;
  const int j = i >> 3;
  const int b = (i & 7) + 8 * (j & 1);
  const int q0 = (j >> 1) * QBLK;
  const int qg = q0 + qw * 32 + ql;

  // ---- Q in registers: B-operand of swapped QK^T. col=q=lane&31, kd=8*hi+jj ----
  const float qscale = 0.08838834764831845f * 1.44269504088896340736f; // 1/sqrt(128)*log2e
  bf16x8 qf[8];
  {
    const float* qrow = Q + (size_t)(b * Sn + qg) * Dn;
#pragma unroll
    for (int dk = 0; dk < 8; ++dk) {
      const int d0 = dk * 16 + hi * 8;
      const float4 a = *(const float4*)(qrow + d0);
      const float4 d = *(const float4*)(qrow + d0 + 4);
      bf16x8 q8;
      q8[0] = (short)f2bf_u(a.x * qscale); q8[1] = (short)f2bf_u(a.y * qscale);
      q8[2] = (short)f2bf_u(a.z * qscale); q8[3] = (short)f2bf_u(a.w * qscale);
      q8[4] = (short)f2bf_u(d.x * qscale); q8[5] = (short)f2bf_u(d.y * qscale);
      q8[6] = (short)f2bf_u(d.z * qscale); q8[7] = (short)f2bf_u(d.w * qscale);
      qf[dk] = q8;
    }
  }

  f32x16 o[4];
#pragma unroll
  for (int dt = 0; dt < 4; ++dt) {
#pragma unroll
    for (int jj = 0; jj < 16; ++jj) o[dt][jj] = 0.f;
  }
  float m_r = -1.0e30f, l_r = 0.f;

  const char* Kg = (const char*)(Kb + (size_t)b * Sn * Dn);   // 32 x 16KB tiles
  const char* Vg = (const char*)(Vf + (size_t)b * Sn * Dn);   // 32 x 16KB tiles

  // async K staging: wave w copies rows [16w,16w+16) = 4KB, 4 x 16B per lane.
#define STAGE_K(t_, dstoff_)                                                   \
  {                                                                            \
    const char* gsrc = Kg + (size_t)(t_)*16384 + w * 4096 + lane * 16;         \
    char* ldst = smem + (dstoff_) + w * 4096;                                  \
    _Pragma("unroll") for (int it = 0; it < 4; ++it) {                         \
      __builtin_amdgcn_global_load_lds(                                        \
          (const __attribute__((address_space(1))) uint32_t*)(gsrc + it * 1024),\
          (__attribute__((address_space(3))) uint32_t*)(ldst + it * 1024),     \
          16, 0, 0);                                                           \
    }                                                                          \
  }

  STAGE_K(0, 0)
  __syncthreads();   // drains vmcnt(0): tile 0 resident

  for (int t = 0; t < NT; ++t) {
    const uint32_t cb = (uint32_t)(t & 1) * 16384;
    if (t < NT - 1) STAGE_K(t + 1, 16384 - cb)   // async; drains at loop barrier

    // ---- V fragments: 8 dense 16B loads (lane-major prepass layout);
    //      latency hides under QK^T + softmax ----
    bf16x8 vfr[8];
    {
      const char* vt = Vg + (size_t)t * 16384 + h * 8192 + lane * 16;
#pragma unroll
      for (int f3 = 0; f3 < 8; ++f3)
        vfr[f3] = *(const bf16x8*)(vt + f3 * 1024);
    }

    // ---- swapped QK^T: S^T[k'][q] over this wave's 32-row k-subset ----
    f32x16 s;
#pragma unroll
    for (int jj = 0; jj < 16; ++jj) s[jj] = 0.f;
    __builtin_amdgcn_s_setprio(1);
#pragma unroll
    for (int dk = 0; dk < 8; ++dk) {
      const uint32_t koff =
          (uint32_t)((32 * h + ql) * 256 + dk * 32 + hi * 16) ^
          ((uint32_t)(ql & 7) << 4);
      bf16x8 a = *(const bf16x8*)(smem + cb + koff);
      s = __builtin_amdgcn_mfma_f32_32x32x16_bf16(a, qf[dk], s, 0, 0, 0);
    }
    __builtin_amdgcn_s_setprio(0);
    // lane holds, for q=ql: k' = 32h + (r&3) + 8*(r>>2) + 4*hi, r=0..15

    // ---- in-register online softmax (per-wave m,l over its k') ----
    float x0 = fmaxf(fmaxf(s[0], s[1]), fmaxf(s[2], s[3]));
    float x1 = fmaxf(fmaxf(s[4], s[5]), fmaxf(s[6], s[7]));
    float x2 = fmaxf(fmaxf(s[8], s[9]), fmaxf(s[10], s[11]));
    float x3 = fmaxf(fmaxf(s[12], s[13]), fmaxf(s[14], s[15]));
    float pm = fmaxf(fmaxf(x0, x1), fmaxf(x2, x3));
    pm = fmaxf(pm, __shfl_xor(pm, 32, 64));

    if (!__all(pm <= m_r + 8.0f)) {   // defer-max (T13)
      const float mnew = fmaxf(m_r, pm);
      const float alpha = __builtin_amdgcn_exp2f(m_r - mnew);
      l_r *= alpha;
#pragma unroll
      for (int dt = 0; dt < 4; ++dt) o[dt] *= alpha;
      m_r = mnew;
    }

#pragma unroll
    for (int jj = 0; jj < 16; ++jj) s[jj] = __builtin_amdgcn_exp2f(s[jj] - m_r);
    {
      float r0 = 0.f, r1 = 0.f, r2 = 0.f, r3 = 0.f;
#pragma unroll
      for (int jj = 0; jj < 4; ++jj) {
        r0 += s[jj]; r1 += s[4 + jj]; r2 += s[8 + jj]; r3 += s[12 + jj];
      }
      float rsum = (r0 + r1) + (r2 + r3);
      l_r += rsum + __shfl_xor(rsum, 32, 64);
    }

    // ---- pack P to bf16 + half-exchange with lane^32 -> PV B-fragments ----
    uint32_t own[4][2];
#pragma unroll
    for (int mm = 0; mm < 4; ++mm) {
      own[mm][0] = pk2(s[4 * mm + 0], s[4 * mm + 1]);
      own[mm][1] = pk2(s[4 * mm + 2], s[4 * mm + 3]);
    }
    uint32_t rcv[2][2];
#pragma unroll
    for (int jj = 0; jj < 2; ++jj)
#pragma unroll
      for (int e = 0; e < 2; ++e) {
        uint32_t sel = hi ? own[2 * jj][e] : own[2 * jj + 1][e];
        rcv[jj][e] = (uint32_t)__shfl_xor((int)sel, 32, 64);
      }
    bf16x8 pb[2];
#pragma unroll
    for (int ks = 0; ks < 2; ++ks) {
      union { uint32_t u[4]; bf16x8 v; } tt;
      tt.u[0] = hi ? rcv[ks][0] : own[2 * ks][0];
      tt.u[1] = hi ? rcv[ks][1] : own[2 * ks][1];
      tt.u[2] = hi ? own[2 * ks + 1][0] : rcv[ks][0];
      tt.u[3] = hi ? own[2 * ks + 1][1] : rcv[ks][1];
      pb[ks] = tt.v;
    }

    // ---- PV as O^T = V^T·P^T: A-frags direct from prepass registers ----
    __builtin_amdgcn_s_setprio(1);
#pragma unroll
    for (int dt = 0; dt < 4; ++dt) {
#pragma unroll
      for (int ks = 0; ks < 2; ++ks) {
        o[dt] = __builtin_amdgcn_mfma_f32_32x32x16_bf16(vfr[dt * 2 + ks], pb[ks],
                                                        o[dt], 0, 0, 0);
      }
    }
    __builtin_amdgcn_s_setprio(0);

    __syncthreads();   // drains vmcnt(0): staged tile t+1 resident; readers done
  }

  // ---- merge the two k-subset partials (w <-> w^2) in LDS, then store ----
  char* xch = smem + qw * 16896;
  if (h) {                       // k-half 1: writer
#pragma unroll
    for (int dt = 0; dt < 4; ++dt) {
#pragma unroll
      for (int q2 = 0; q2 < 4; ++q2) {
        float4 v;
        v.x = o[dt][4 * q2 + 0]; v.y = o[dt][4 * q2 + 1];
        v.z = o[dt][4 * q2 + 2]; v.w = o[dt][4 * q2 + 3];
        *(float4*)(xch + (dt * 4 + q2) * 1024 + lane * 16) = v;
      }
    }
    *(float2*)(xch + 16384 + lane * 8) = make_float2(m_r, l_r);
  }
  __syncthreads();
  if (!h) {                      // k-half 0: merger + storer
    const float2 ml1v = *(const float2*)(xch + 16384 + lane * 8);
    const float M = fmaxf(m_r, ml1v.x);
    const float w0 = __builtin_amdgcn_exp2f(m_r - M);
    const float w1 = __builtin_amdgcn_exp2f(ml1v.x - M);
    const float inv = 1.0f / (l_r * w0 + ml1v.y * w1);
    const float s0 = w0 * inv, s1 = w1 * inv;
    float* orow = O + (size_t)(b * Sn + qg) * Dn;
#pragma unroll
    for (int dt = 0; dt < 4; ++dt) {
#pragma unroll
      for (int q2 = 0; q2 < 4; ++q2) {
        const float4 o1v =
            *(const float4*)(xch + (dt * 4 + q2) * 1024 + lane * 16);
        float4 v;
        v.x = o[dt][4 * q2 + 0] * s0 + o1v.x * s1;
        v.y = o[dt][4 * q2 + 1] * s0 + o1v.y * s1;
        v.z = o[dt][4 * q2 + 2] * s0 + o1v.z * s1;
        v.w = o[dt][4 * q2 + 3] * s0 + o1v.w * s1;
        *(float4*)(orow + dt * 32 + q2 * 8 + hi * 4) = v;
      }
    }
  }
}

extern "C" void kernel_launch(void* const* d_in, const int* in_sizes, int n_in,
                              void* d_out, int out_size, void* d_ws, size_t ws_size,
                              hipStream_t stream) {
  (void)in_sizes; (void)n_in; (void)out_size; (void)ws_size;
  const float* Q = (const float*)d_in[0];
  const float* K = (const float*)d_in[1];
  const float* V = (const float*)d_in[2];
  float* O = (float*)d_out;

  // ws: Kb (8.39 MB pre-swizzled bf16 K) | Vf (8.39 MB PV-fragment bf16 V)
  unsigned short* Kb = (unsigned short*)d_ws;
  unsigned short* Vf = Kb + (size_t)Bn * Sn * Dn;

  cvt_k<<<dim3(2048, 1, 1), dim3(256, 1, 1), 0, stream>>>(K, Kb);
  tr_v<<<dim3(Bn * 32, 1, 1), dim3(256, 1, 1), 0, stream>>>(V, Vf);
  attn_fwd<<<dim3((Sn / QBLK) * Bn, 1, 1), dim3(NTHR, 1, 1), 0, stream>>>(
      Q, Kb, Vf, O);
}

// Round 16
// 68.203 us; speedup vs baseline: 2.5546x; 1.0122x over previous
//
#include <hip/hip_runtime.h>
#include <stdint.h>

#define Bn 16
#define Sn 2048
#define Dn 128
#define QBLK 64
#define KVBLK 64
#define NTHR 256
#define NT (Sn / KVBLK)

typedef __attribute__((ext_vector_type(4))) float f32x4;
typedef __attribute__((ext_vector_type(16))) float f32x16;
typedef __attribute__((ext_vector_type(8))) short bf16x8;   // 8 bf16 = 4 VGPRs
typedef __attribute__((ext_vector_type(2))) unsigned int u32x2;

// LDS: epilogue exchange only (two 16896 B regions, qw-indexed)
#define SMEM_BYTES 33792

__device__ __forceinline__ uint32_t f2bf_u(float f) {   // fp32 -> bf16, round-nearest-away
  return (__float_as_uint(f) + 0x8000u) >> 16;
}
__device__ __forceinline__ uint32_t pk2(float a, float b) {
  return f2bf_u(a) | (f2bf_u(b) << 16);
}

// ---- prepass 1: K fp32 -> bf16 QK^T-fragment layout ----
// Kf[b][t][h<2][dk<8][lane<64][8 bf16]: granule(h,dk,lane) holds
// K[t*64 + 32h + (lane&31)][dk*16 + 8*(lane>>5) + j], j=0..7
__global__ __launch_bounds__(256) void tr_k(const float* __restrict__ K,
                                            unsigned short* __restrict__ Kf) {
  __shared__ unsigned short lds[64 * 136];   // [k][d], stride 136 elems
  const int tid = threadIdx.x;
  const float* src = K + (size_t)blockIdx.x * (64 * Dn);
#pragma unroll
  for (int it = 0; it < 8; ++it) {
    const int gr = it * 256 + tid;           // float4 granule: 64k x 32
    const int k = gr >> 5, g4 = gr & 31;
    const float4 v = ((const float4*)src)[gr];
    unsigned short* p = &lds[k * 136 + g4 * 4];
    p[0] = (unsigned short)f2bf_u(v.x);
    p[1] = (unsigned short)f2bf_u(v.y);
    p[2] = (unsigned short)f2bf_u(v.z);
    p[3] = (unsigned short)f2bf_u(v.w);
  }
  __syncthreads();
  char* dst = (char*)Kf + (size_t)blockIdx.x * 16384;
#pragma unroll
  for (int it = 0; it < 4; ++it) {
    const int g = it * 256 + tid;            // granule id 0..1023
    const int lane = g & 63, dk = (g >> 6) & 7, h = g >> 9;
    const int row = 32 * h + (lane & 31);
    const int d0 = dk * 16 + 8 * (lane >> 5);
    const unsigned short* p = &lds[row * 136 + d0];
    uint4 o;
    o.x = (uint32_t)p[0] | ((uint32_t)p[1] << 16);
    o.y = (uint32_t)p[2] | ((uint32_t)p[3] << 16);
    o.z = (uint32_t)p[4] | ((uint32_t)p[5] << 16);
    o.w = (uint32_t)p[6] | ((uint32_t)p[7] << 16);
    *(uint4*)(dst + g * 16) = o;
  }
}

// ---- prepass 2: V fp32 -> bf16 PV-fragment layout ----
// Vf[b][t][h<2][f3<8][lane<64][8 bf16]: granule(h,f3,lane) holds
// V[t*64 + 32h + (f3&1)*16 + 8*(lane>>5) + j][(f3>>1)*32 + (lane&31)], j=0..7
__global__ __launch_bounds__(256) void tr_v(const float* __restrict__ V,
                                            unsigned short* __restrict__ Vf) {
  __shared__ unsigned short lds[64 * 130];   // [k][d], stride 130 elems
  const int tid = threadIdx.x;
  const float* src = V + (size_t)blockIdx.x * (64 * Dn);
#pragma unroll
  for (int it = 0; it < 8; ++it) {
    const int gr = it * 256 + tid;
    const int k = gr >> 5, g4 = gr & 31;
    const float4 v = ((const float4*)src)[gr];
    unsigned short* p = &lds[k * 130 + g4 * 4];
    p[0] = (unsigned short)f2bf_u(v.x);
    p[1] = (unsigned short)f2bf_u(v.y);
    p[2] = (unsigned short)f2bf_u(v.z);
    p[3] = (unsigned short)f2bf_u(v.w);
  }
  __syncthreads();
  char* dst = (char*)Vf + (size_t)blockIdx.x * 16384;
#pragma unroll
  for (int it = 0; it < 4; ++it) {
    const int g = it * 256 + tid;
    const int lane = g & 63, f3 = (g >> 6) & 7, h = g >> 9;
    const int d = (f3 >> 1) * 32 + (lane & 31);
    const int k0 = 32 * h + (f3 & 1) * 16 + 8 * (lane >> 5);
    uint4 o;
    o.x = (uint32_t)lds[(k0 + 0) * 130 + d] | ((uint32_t)lds[(k0 + 1) * 130 + d] << 16);
    o.y = (uint32_t)lds[(k0 + 2) * 130 + d] | ((uint32_t)lds[(k0 + 3) * 130 + d] << 16);
    o.z = (uint32_t)lds[(k0 + 4) * 130 + d] | ((uint32_t)lds[(k0 + 5) * 130 + d] << 16);
    o.w = (uint32_t)lds[(k0 + 6) * 130 + d] | ((uint32_t)lds[(k0 + 7) * 130 + d] << 16);
    *(uint4*)(dst + g * 16) = o;
  }
}

__global__ __launch_bounds__(NTHR, 2) void attn_fwd(
    const float* __restrict__ Q, const unsigned short* __restrict__ Kf,
    const unsigned short* __restrict__ Vf, float* __restrict__ O) {
  __shared__ uint4 smem_[SMEM_BYTES / 16];
  char* smem = (char*)smem_;

  const int tid = threadIdx.x;
  const int lane = tid & 63;
  const int w = tid >> 6;        // wave 0..3
  const int qw = w & 1;          // q sub-tile (32 rows)
  const int h = w >> 1;          // k sub-range of tile (32 rows)
  const int hi = lane >> 5;      // half-wave 0/1
  const int ql = lane & 31;      // q selector

  // XCD-aware swizzle: i&7 -> XCD; each XCD's L2 holds ~2 batches' Kf/Vf.
  const int i = blockIdx.x;
  const int j = i >> 3;
  const int b = (i & 7) + 8 * (j & 1);
  const int q0 = (j >> 1) * QBLK;
  const int qg = q0 + qw * 32 + ql;

  // ---- Q in registers: B-operand of swapped QK^T. col=q=lane&31, kd=8*hi+jj ----
  const float qscale = 0.08838834764831845f * 1.44269504088896340736f; // 1/sqrt(128)*log2e
  bf16x8 qf[8];
  {
    const float* qrow = Q + (size_t)(b * Sn + qg) * Dn;
#pragma unroll
    for (int dk = 0; dk < 8; ++dk) {
      const int d0 = dk * 16 + hi * 8;
      const float4 a = *(const float4*)(qrow + d0);
      const float4 d = *(const float4*)(qrow + d0 + 4);
      bf16x8 q8;
      q8[0] = (short)f2bf_u(a.x * qscale); q8[1] = (short)f2bf_u(a.y * qscale);
      q8[2] = (short)f2bf_u(a.z * qscale); q8[3] = (short)f2bf_u(a.w * qscale);
      q8[4] = (short)f2bf_u(d.x * qscale); q8[5] = (short)f2bf_u(d.y * qscale);
      q8[6] = (short)f2bf_u(d.z * qscale); q8[7] = (short)f2bf_u(d.w * qscale);
      qf[dk] = q8;
    }
  }

  f32x16 o[4];
#pragma unroll
  for (int dt = 0; dt < 4; ++dt) {
#pragma unroll
    for (int jj = 0; jj < 16; ++jj) o[dt][jj] = 0.f;
  }
  float m_r = -1.0e30f, l_r = 0.f;

  const char* Kg = (const char*)(Kf + (size_t)b * Sn * Dn);   // 32 x 16KB tiles
  const char* Vg = (const char*)(Vf + (size_t)b * Sn * Dn);   // 32 x 16KB tiles

  // no barriers, no LDS in the main loop: each wave fully independent
#pragma unroll 2
  for (int t = 0; t < NT; ++t) {
    // ---- K and V fragments: 16 dense 16B loads (prepass layouts) ----
    bf16x8 kfr[8], vfr[8];
    {
      const char* kt = Kg + (size_t)t * 16384 + h * 8192 + lane * 16;
      const char* vt = Vg + (size_t)t * 16384 + h * 8192 + lane * 16;
#pragma unroll
      for (int f = 0; f < 8; ++f) kfr[f] = *(const bf16x8*)(kt + f * 1024);
#pragma unroll
      for (int f = 0; f < 8; ++f) vfr[f] = *(const bf16x8*)(vt + f * 1024);
    }

    // ---- swapped QK^T: S^T[k'][q] over this wave's 32-row k-subset ----
    f32x16 s;
#pragma unroll
    for (int jj = 0; jj < 16; ++jj) s[jj] = 0.f;
    __builtin_amdgcn_s_setprio(1);
#pragma unroll
    for (int dk = 0; dk < 8; ++dk)
      s = __builtin_amdgcn_mfma_f32_32x32x16_bf16(kfr[dk], qf[dk], s, 0, 0, 0);
    __builtin_amdgcn_s_setprio(0);
    // lane holds, for q=ql: k' = 32h + (r&3) + 8*(r>>2) + 4*hi, r=0..15

    // ---- in-register online softmax (per-wave m,l over its k') ----
    float x0 = fmaxf(fmaxf(s[0], s[1]), fmaxf(s[2], s[3]));
    float x1 = fmaxf(fmaxf(s[4], s[5]), fmaxf(s[6], s[7]));
    float x2 = fmaxf(fmaxf(s[8], s[9]), fmaxf(s[10], s[11]));
    float x3 = fmaxf(fmaxf(s[12], s[13]), fmaxf(s[14], s[15]));
    float pm = fmaxf(fmaxf(x0, x1), fmaxf(x2, x3));
    pm = fmaxf(pm, __shfl_xor(pm, 32, 64));

    if (!__all(pm <= m_r + 8.0f)) {   // defer-max (T13)
      const float mnew = fmaxf(m_r, pm);
      const float alpha = __builtin_amdgcn_exp2f(m_r - mnew);
      l_r *= alpha;
#pragma unroll
      for (int dt = 0; dt < 4; ++dt) o[dt] *= alpha;
      m_r = mnew;
    }

#pragma unroll
    for (int jj = 0; jj < 16; ++jj) s[jj] = __builtin_amdgcn_exp2f(s[jj] - m_r);
    {
      float r0 = 0.f, r1 = 0.f, r2 = 0.f, r3 = 0.f;
#pragma unroll
      for (int jj = 0; jj < 4; ++jj) {
        r0 += s[jj]; r1 += s[4 + jj]; r2 += s[8 + jj]; r3 += s[12 + jj];
      }
      float rsum = (r0 + r1) + (r2 + r3);
      l_r += rsum + __shfl_xor(rsum, 32, 64);
    }

    // ---- pack P to bf16 + half-exchange with lane^32 -> PV B-fragments ----
    uint32_t own[4][2];
#pragma unroll
    for (int mm = 0; mm < 4; ++mm) {
      own[mm][0] = pk2(s[4 * mm + 0], s[4 * mm + 1]);
      own[mm][1] = pk2(s[4 * mm + 2], s[4 * mm + 3]);
    }
    uint32_t rcv[2][2];
#pragma unroll
    for (int jj = 0; jj < 2; ++jj)
#pragma unroll
      for (int e = 0; e < 2; ++e) {
        uint32_t sel = hi ? own[2 * jj][e] : own[2 * jj + 1][e];
        rcv[jj][e] = (uint32_t)__shfl_xor((int)sel, 32, 64);
      }
    bf16x8 pb[2];
#pragma unroll
    for (int ks = 0; ks < 2; ++ks) {
      union { uint32_t u[4]; bf16x8 v; } tt;
      tt.u[0] = hi ? rcv[ks][0] : own[2 * ks][0];
      tt.u[1] = hi ? rcv[ks][1] : own[2 * ks][1];
      tt.u[2] = hi ? own[2 * ks + 1][0] : rcv[ks][0];
      tt.u[3] = hi ? own[2 * ks + 1][1] : rcv[ks][1];
      pb[ks] = tt.v;
    }

    // ---- PV as O^T = V^T·P^T: A-frags direct from prepass registers ----
    __builtin_amdgcn_s_setprio(1);
#pragma unroll
    for (int dt = 0; dt < 4; ++dt) {
#pragma unroll
      for (int ks = 0; ks < 2; ++ks) {
        o[dt] = __builtin_amdgcn_mfma_f32_32x32x16_bf16(vfr[dt * 2 + ks], pb[ks],
                                                        o[dt], 0, 0, 0);
      }
    }
    __builtin_amdgcn_s_setprio(0);
  }

  // ---- merge the two k-subset partials (w <-> w^2) in LDS, then store ----
  __syncthreads();
  char* xch = smem + qw * 16896;
  if (h) {                       // k-half 1: writer
#pragma unroll
    for (int dt = 0; dt < 4; ++dt) {
#pragma unroll
      for (int q2 = 0; q2 < 4; ++q2) {
        float4 v;
        v.x = o[dt][4 * q2 + 0]; v.y = o[dt][4 * q2 + 1];
        v.z = o[dt][4 * q2 + 2]; v.w = o[dt][4 * q2 + 3];
        *(float4*)(xch + (dt * 4 + q2) * 1024 + lane * 16) = v;
      }
    }
    *(float2*)(xch + 16384 + lane * 8) = make_float2(m_r, l_r);
  }
  __syncthreads();
  if (!h) {                      // k-half 0: merger + storer
    const float2 ml1v = *(const float2*)(xch + 16384 + lane * 8);
    const float M = fmaxf(m_r, ml1v.x);
    const float w0 = __builtin_amdgcn_exp2f(m_r - M);
    const float w1 = __builtin_amdgcn_exp2f(ml1v.x - M);
    const float inv = 1.0f / (l_r * w0 + ml1v.y * w1);
    const float s0 = w0 * inv, s1 = w1 * inv;
    float* orow = O + (size_t)(b * Sn + qg) * Dn;
#pragma unroll
    for (int dt = 0; dt < 4; ++dt) {
#pragma unroll
      for (int q2 = 0; q2 < 4; ++q2) {
        const float4 o1v =
            *(const float4*)(xch + (dt * 4 + q2) * 1024 + lane * 16);
        float4 v;
        v.x = o[dt][4 * q2 + 0] * s0 + o1v.x * s1;
        v.y = o[dt][4 * q2 + 1] * s0 + o1v.y * s1;
        v.z = o[dt][4 * q2 + 2] * s0 + o1v.z * s1;
        v.w = o[dt][4 * q2 + 3] * s0 + o1v.w * s1;
        *(float4*)(orow + dt * 32 + q2 * 8 + hi * 4) = v;
      }
    }
  }
}

extern "C" void kernel_launch(void* const* d_in, const int* in_sizes, int n_in,
                              void* d_out, int out_size, void* d_ws, size_t ws_size,
                              hipStream_t stream) {
  (void)in_sizes; (void)n_in; (void)out_size; (void)ws_size;
  const float* Q = (const float*)d_in[0];
  const float* K = (const float*)d_in[1];
  const float* V = (const float*)d_in[2];
  float* O = (float*)d_out;

  // ws: Kf (8.39 MB fragment bf16 K) | Vf (8.39 MB fragment bf16 V)
  unsigned short* Kf = (unsigned short*)d_ws;
  unsigned short* Vf = Kf + (size_t)Bn * Sn * Dn;

  tr_k<<<dim3(Bn * 32, 1, 1), dim3(256, 1, 1), 0, stream>>>(K, Kf);
  tr_v<<<dim3(Bn * 32, 1, 1), dim3(256, 1, 1), 0, stream>>>(V, Vf);
  attn_fwd<<<dim3((Sn / QBLK) * Bn, 1, 1), dim3(NTHR, 1, 1), 0, stream>>>(
      Q, Kf, Vf, O);
}